// Round 2
// baseline (257.061 us; speedup 1.0000x reference)
//
#include <hip/hip_runtime.h>

#define B 64
#define N 2048
#define E 32768
#define D 256
#define H 256
#define GCH 32         // gather blocks per batch (64 rows per block; 2048 blocks)

// ---------------------------------------------------------------------------
// Fused edge pipeline: one block per batch, both passes in LDS.
//   pass 1: w[n]  = sum_{e: row<L, col==n} val[e];   sw = sum_{e: row<L} val[e]
//   pass 2: z[m]  = sum_{e: col==m} w[row[e]] * val[e]
// Replaces edge_w + edge_z: removes the 8-way w_part round trip (4 MB write +
// 32 MB amplified re-read), the second HBM pass over adj (pass 2 hits L2:
// 8 blocks/XCD x 384 KB = 3 MB < 4 MB), and one kernel launch.
// ---------------------------------------------------------------------------
__global__ __launch_bounds__(1024) void edges_fused_kernel(
    const int* __restrict__ adj_row, const int* __restrict__ adj_col,
    const float* __restrict__ adj_val, const int* __restrict__ cur_len,
    float* __restrict__ z, float* __restrict__ sw)
{
    __shared__ float wloc[N];      // 8 KB
    __shared__ float zloc[N];      // 8 KB
    __shared__ float sred[16];     // one slot per wave
    const int b = blockIdx.x, tid = threadIdx.x;
    const int L = *cur_len;

    if (tid < N / 4) {             // 512 threads each clear one float4 of both
        ((float4*)wloc)[tid] = make_float4(0.f, 0.f, 0.f, 0.f);
        ((float4*)zloc)[tid] = make_float4(0.f, 0.f, 0.f, 0.f);
    }
    __syncthreads();

    const int4*   row4 = (const int4*)  (adj_row + (size_t)b * E);
    const int4*   col4 = (const int4*)  (adj_col + (size_t)b * E);
    const float4* val4 = (const float4*)(adj_val + (size_t)b * E);

    // ---- pass 1: w histogram + sw partial ----
    float svp = 0.f;
    #pragma unroll 4
    for (int k = 0; k < E / 4 / 1024; ++k) {       // 8 iterations
        const int    i = tid + k * 1024;
        const int4   r = row4[i];
        const int4   c = col4[i];
        const float4 v = val4[i];
        if (r.x < L) { atomicAdd(&wloc[c.x], v.x); svp += v.x; }
        if (r.y < L) { atomicAdd(&wloc[c.y], v.y); svp += v.y; }
        if (r.z < L) { atomicAdd(&wloc[c.z], v.z); svp += v.z; }
        if (r.w < L) { atomicAdd(&wloc[c.w], v.w); svp += v.w; }
    }
    for (int off = 32; off; off >>= 1) svp += __shfl_down(svp, off, 64);
    if ((tid & 63) == 0) sred[tid >> 6] = svp;
    __syncthreads();                                // publishes wloc + sred

    // ---- pass 2: z histogram (adj re-read from L2) ----
    #pragma unroll 4
    for (int k = 0; k < E / 4 / 1024; ++k) {       // 8 iterations
        const int    i = tid + k * 1024;
        const int4   r = row4[i];
        const int4   c = col4[i];
        const float4 v = val4[i];
        float wv;
        wv = wloc[r.x]; if (wv != 0.f) atomicAdd(&zloc[c.x], wv * v.x);
        wv = wloc[r.y]; if (wv != 0.f) atomicAdd(&zloc[c.y], wv * v.y);
        wv = wloc[r.z]; if (wv != 0.f) atomicAdd(&zloc[c.z], wv * v.z);
        wv = wloc[r.w]; if (wv != 0.f) atomicAdd(&zloc[c.w], wv * v.w);
    }
    __syncthreads();

    if (tid < N / 4)
        ((float4*)(z + (size_t)b * N))[tid] = ((const float4*)zloc)[tid];
    if (tid == 0) {
        float s = 0.f;
        #pragma unroll
        for (int i = 0; i < 16; ++i) s += sred[i];
        sw[b] = s;
    }
}

// ---------------------------------------------------------------------------
// Gather: u_part[b,g,:] = sum_{n in 64-row group g} z[b,n]*emb[neighbors[b,n],:]
// Grid (B, 32) = 2048 blocks -> 8 blocks/CU (full 32-wave occupancy; the
// loop is latency-bound per prior counters, so wave count is the lever).
// One wave per row: lane = float4 offset -> coalesced 1KB row reads.
// Unchanged from the 222 us version except z is now a single final array.
// ---------------------------------------------------------------------------
__global__ __launch_bounds__(256) void gather_kernel(
    const int* __restrict__ neighbors, const float* __restrict__ emb,
    const float* __restrict__ z, float* __restrict__ u_part)
{
    const int b = blockIdx.x, grp = blockIdx.y, tid = threadIdx.x;
    const int lane = tid & 63, rg = tid >> 6;
    const int n0 = grp * 64;                  // 64 rows per block

    __shared__ float zh[64];
    __shared__ int   ns[64];
    if (tid < 64) {
        zh[tid] = z[(size_t)b * N + n0 + tid];
        ns[tid] = neighbors[(size_t)b * N + n0 + tid];
    }
    __syncthreads();

    const float4* __restrict__ emb4 = (const float4*)emb;
    float4 a0 = make_float4(0.f,0.f,0.f,0.f), a1 = a0, a2 = a0, a3 = a0;

    #pragma unroll
    for (int i = 0; i < 16; ++i) {            // 16 rows per wave
        const int j = i * 4 + rg;
        const float zv = zh[j];
        const size_t idx = (size_t)ns[j];
        const float4 v = emb4[idx * (D / 4) + lane];
        if ((i & 3) == 0)      { a0.x += zv*v.x; a0.y += zv*v.y; a0.z += zv*v.z; a0.w += zv*v.w; }
        else if ((i & 3) == 1) { a1.x += zv*v.x; a1.y += zv*v.y; a1.z += zv*v.z; a1.w += zv*v.w; }
        else if ((i & 3) == 2) { a2.x += zv*v.x; a2.y += zv*v.y; a2.z += zv*v.z; a2.w += zv*v.w; }
        else                   { a3.x += zv*v.x; a3.y += zv*v.y; a3.z += zv*v.z; a3.w += zv*v.w; }
    }
    float4 acc = make_float4(a0.x+a1.x+a2.x+a3.x, a0.y+a1.y+a2.y+a3.y,
                             a0.z+a1.z+a2.z+a3.z, a0.w+a1.w+a2.w+a3.w);

    __shared__ float4 red[256];
    red[tid] = acc;
    __syncthreads();
    if (tid < 64) {
        float4 a = red[tid], bb = red[tid + 64], c = red[tid + 128], d = red[tid + 192];
        float4 s = make_float4(a.x + bb.x + c.x + d.x, a.y + bb.y + c.y + d.y,
                               a.z + bb.z + c.z + d.z, a.w + bb.w + c.w + d.w);
        ((float4*)u_part)[((size_t)b * GCH + grp) * (D / 4) + tid] = s;
    }
}

// ---------------------------------------------------------------------------
// Head: u = sum_g u_part ; y = u@W1 + sw*b1 ; p = y@W2/L + b2 ;
//       out = relu(p@fc1_w + fc1_b).
// 1024 threads: t = output col, s = 4-way k-split. sw now a single scalar.
// ---------------------------------------------------------------------------
__global__ __launch_bounds__(1024) void head_kernel(
    const float* __restrict__ u_part, const float* __restrict__ sw_arr,
    const float* __restrict__ W1, const float* __restrict__ b1,
    const float* __restrict__ W2, const float* __restrict__ b2,
    const float* __restrict__ fc1_w, const float* __restrict__ fc1_b,
    const int* __restrict__ cur_len, float* __restrict__ out)
{
    const int b = blockIdx.x;
    const int t = threadIdx.x & 255;   // output column
    const int s = threadIdx.x >> 8;    // k-split group (0..3)
    __shared__ float red[4][256];
    __shared__ float su[D];
    __shared__ float sy[H];
    __shared__ float sp[H];

    float part = 0.f;
    #pragma unroll
    for (int c = 0; c < GCH / 4; ++c)
        part += u_part[((size_t)b * GCH + s * (GCH / 4) + c) * D + t];
    red[s][t] = part;
    __syncthreads();
    if (s == 0) su[t] = red[0][t] + red[1][t] + red[2][t] + red[3][t];
    __syncthreads();

    part = 0.f;
    #pragma unroll 8
    for (int k = 0; k < 64; ++k) {
        const int d = s * 64 + k;
        part += su[d] * W1[d * H + t];
    }
    red[s][t] = part;
    __syncthreads();
    if (s == 0)
        sy[t] = red[0][t] + red[1][t] + red[2][t] + red[3][t] + sw_arr[b] * b1[t];
    __syncthreads();

    const float invL = 1.f / (float)(*cur_len);
    part = 0.f;
    #pragma unroll 8
    for (int k = 0; k < 64; ++k) {
        const int d = s * 64 + k;
        part += sy[d] * W2[d * H + t];
    }
    red[s][t] = part;
    __syncthreads();
    if (s == 0)
        sp[t] = (red[0][t] + red[1][t] + red[2][t] + red[3][t]) * invL + b2[t];
    __syncthreads();

    part = 0.f;
    #pragma unroll 8
    for (int k = 0; k < 64; ++k) {
        const int d = s * 64 + k;
        part += sp[d] * fc1_w[d * H + t];
    }
    red[s][t] = part;
    __syncthreads();
    if (s == 0) {
        const float v = red[0][t] + red[1][t] + red[2][t] + red[3][t] + fc1_b[t];
        out[(size_t)b * H + t] = fmaxf(v, 0.f);
    }
}

extern "C" void kernel_launch(void* const* d_in, const int* in_sizes, int n_in,
                              void* d_out, int out_size, void* d_ws, size_t ws_size,
                              hipStream_t stream) {
    const int*   neighbors = (const int*)  d_in[0];
    const int*   adj_row   = (const int*)  d_in[1];
    const int*   adj_col   = (const int*)  d_in[2];
    const float* adj_val   = (const float*)d_in[3];
    const float* emb_table = (const float*)d_in[4];
    const float* W1        = (const float*)d_in[5];
    const float* b1        = (const float*)d_in[6];
    const float* W2        = (const float*)d_in[7];
    const float* b2        = (const float*)d_in[8];
    const float* fc1_w     = (const float*)d_in[9];
    const float* fc1_b     = (const float*)d_in[10];
    const int*   cur_len   = (const int*)  d_in[11];
    float*       out       = (float*)d_out;

    // workspace layout (floats), all fully overwritten every call (no memset):
    // [z: B*N][sw: B][u_part: B*GCH*D]
    float* z_ws  = (float*)d_ws;
    float* sw_ws = z_ws + (size_t)B * N;          // 512 KB in -> 16B aligned
    float* u_ws  = sw_ws + B;                     // +256 B -> 16B aligned

    edges_fused_kernel<<<B, 1024, 0, stream>>>(adj_row, adj_col, adj_val,
                                               cur_len, z_ws, sw_ws);
    gather_kernel<<<dim3(B, GCH), 256, 0, stream>>>(neighbors, emb_table, z_ws, u_ws);
    head_kernel<<<B, 1024, 0, stream>>>(u_ws, sw_ws, W1, b1, W2, b2,
                                        fc1_w, fc1_b, cur_len, out);
}

// Round 3
// 244.111 us; speedup vs baseline: 1.0530x; 1.0530x over previous
//
#include <hip/hip_runtime.h>

#define B 64
#define N 2048
#define E 32768
#define D 256
#define H 256
#define SEG 8          // edge segments per batch
#define EPB (E / SEG)  // 4096 edges per block
#define GCH 32         // gather blocks per batch (64 rows per block; 2048 blocks)

// ---------------------------------------------------------------------------
// Zero w and z (adjacent in workspace: 2*B*N floats = 1 MB).
// Needed because edge kernels flush via global atomicAdd.
// ---------------------------------------------------------------------------
__global__ __launch_bounds__(512) void zero_wz_kernel(float* __restrict__ wz)
{
    ((float4*)wz)[blockIdx.x * 512 + threadIdx.x] = make_float4(0.f, 0.f, 0.f, 0.f);
}

// ---------------------------------------------------------------------------
// Edge pass 1 (512 blocks): LDS histogram of w over this segment's edges,
// then flush nonzero bins with global atomicAdd into final w[b][n].
// ~1/4 of edges pass row<L (L=512 of 2048) -> ~1K LDS atomics/block;
// ~61% of bins zero at flush -> ~800 global atomics/block.
// ---------------------------------------------------------------------------
__global__ __launch_bounds__(512) void edge_w_kernel(
    const int* __restrict__ adj_row, const int* __restrict__ adj_col,
    const float* __restrict__ adj_val, const int* __restrict__ cur_len,
    float* __restrict__ w, float* __restrict__ sw_part)
{
    __shared__ float wloc[N];
    __shared__ float sred[8];
    const int b = blockIdx.x, seg = blockIdx.y, tid = threadIdx.x;
    const int L = *cur_len;

    ((float4*)wloc)[tid] = make_float4(0.f, 0.f, 0.f, 0.f);
    __syncthreads();

    const int base = b * E + seg * EPB;            // multiple of 4096 -> aligned
    const int4*   row4 = (const int4*)  (adj_row + base);
    const int4*   col4 = (const int4*)  (adj_col + base);
    const float4* val4 = (const float4*)(adj_val + base);

    float svp = 0.f;
    #pragma unroll
    for (int k = 0; k < EPB / (512 * 4); ++k) {    // 2 iterations
        const int    i = tid + k * 512;
        const int4   r = row4[i];
        const int4   c = col4[i];
        const float4 v = val4[i];
        if (r.x < L) { atomicAdd(&wloc[c.x], v.x); svp += v.x; }
        if (r.y < L) { atomicAdd(&wloc[c.y], v.y); svp += v.y; }
        if (r.z < L) { atomicAdd(&wloc[c.z], v.z); svp += v.z; }
        if (r.w < L) { atomicAdd(&wloc[c.w], v.w); svp += v.w; }
    }
    __syncthreads();

    // flush nonzero bins to global w (device-scope atomics)
    {
        const float4 v = ((const float4*)wloc)[tid];
        float* dst = w + (size_t)b * N + tid * 4;
        if (v.x != 0.f) atomicAdd(dst + 0, v.x);
        if (v.y != 0.f) atomicAdd(dst + 1, v.y);
        if (v.z != 0.f) atomicAdd(dst + 2, v.z);
        if (v.w != 0.f) atomicAdd(dst + 3, v.w);
    }

    for (int off = 32; off; off >>= 1) svp += __shfl_down(svp, off, 64);
    if ((tid & 63) == 0) sred[tid >> 6] = svp;
    __syncthreads();
    if (tid == 0) {
        float s = 0.f;
        #pragma unroll
        for (int i = 0; i < 8; ++i) s += sred[i];
        sw_part[b * SEG + seg] = s;
    }
}

// ---------------------------------------------------------------------------
// Edge pass 2 (512 blocks): load final w[b] (8 KB, L2-resident) into LDS,
// LDS histogram of z over this segment's edges, atomic flush into z[b][m].
// adj re-read is L2/L3-resident (24 MB total, second touch).
// ---------------------------------------------------------------------------
__global__ __launch_bounds__(512) void edge_z_kernel(
    const int* __restrict__ adj_row, const int* __restrict__ adj_col,
    const float* __restrict__ adj_val, const float* __restrict__ w,
    float* __restrict__ z)
{
    __shared__ float wfull[N];
    __shared__ float zloc[N];
    const int b = blockIdx.x, seg = blockIdx.y, tid = threadIdx.x;

    ((float4*)wfull)[tid] = ((const float4*)(w + (size_t)b * N))[tid];
    ((float4*)zloc)[tid]  = make_float4(0.f, 0.f, 0.f, 0.f);
    __syncthreads();

    const int base = b * E + seg * EPB;
    const int4*   row4 = (const int4*)  (adj_row + base);
    const int4*   col4 = (const int4*)  (adj_col + base);
    const float4* val4 = (const float4*)(adj_val + base);

    #pragma unroll
    for (int k = 0; k < EPB / (512 * 4); ++k) {    // 2 iterations
        const int    i = tid + k * 512;
        const int4   r = row4[i];
        const int4   c = col4[i];
        const float4 v = val4[i];
        float wv;
        wv = wfull[r.x]; if (wv != 0.f) atomicAdd(&zloc[c.x], wv * v.x);
        wv = wfull[r.y]; if (wv != 0.f) atomicAdd(&zloc[c.y], wv * v.y);
        wv = wfull[r.z]; if (wv != 0.f) atomicAdd(&zloc[c.z], wv * v.z);
        wv = wfull[r.w]; if (wv != 0.f) atomicAdd(&zloc[c.w], wv * v.w);
    }
    __syncthreads();

    {
        const float4 v = ((const float4*)zloc)[tid];
        float* dst = z + (size_t)b * N + tid * 4;
        if (v.x != 0.f) atomicAdd(dst + 0, v.x);
        if (v.y != 0.f) atomicAdd(dst + 1, v.y);
        if (v.z != 0.f) atomicAdd(dst + 2, v.z);
        if (v.w != 0.f) atomicAdd(dst + 3, v.w);
    }
}

// ---------------------------------------------------------------------------
// Gather: u_part[b,g,:] = sum_{n in 64-row group g} z[b,n]*emb[neighbors[b,n],:]
// Grid (B, 32) = 2048 blocks -> 8 blocks/CU. One wave per row: lane = float4
// offset -> coalesced 1KB row reads. Unchanged (clean A/B on edges).
// ---------------------------------------------------------------------------
__global__ __launch_bounds__(256) void gather_kernel(
    const int* __restrict__ neighbors, const float* __restrict__ emb,
    const float* __restrict__ z, float* __restrict__ u_part)
{
    const int b = blockIdx.x, grp = blockIdx.y, tid = threadIdx.x;
    const int lane = tid & 63, rg = tid >> 6;
    const int n0 = grp * 64;                  // 64 rows per block

    __shared__ float zh[64];
    __shared__ int   ns[64];
    if (tid < 64) {
        zh[tid] = z[(size_t)b * N + n0 + tid];
        ns[tid] = neighbors[(size_t)b * N + n0 + tid];
    }
    __syncthreads();

    const float4* __restrict__ emb4 = (const float4*)emb;
    float4 a0 = make_float4(0.f,0.f,0.f,0.f), a1 = a0, a2 = a0, a3 = a0;

    #pragma unroll
    for (int i = 0; i < 16; ++i) {            // 16 rows per wave
        const int j = i * 4 + rg;
        const float zv = zh[j];
        const size_t idx = (size_t)ns[j];
        const float4 v = emb4[idx * (D / 4) + lane];
        if ((i & 3) == 0)      { a0.x += zv*v.x; a0.y += zv*v.y; a0.z += zv*v.z; a0.w += zv*v.w; }
        else if ((i & 3) == 1) { a1.x += zv*v.x; a1.y += zv*v.y; a1.z += zv*v.z; a1.w += zv*v.w; }
        else if ((i & 3) == 2) { a2.x += zv*v.x; a2.y += zv*v.y; a2.z += zv*v.z; a2.w += zv*v.w; }
        else                   { a3.x += zv*v.x; a3.y += zv*v.y; a3.z += zv*v.z; a3.w += zv*v.w; }
    }
    float4 acc = make_float4(a0.x+a1.x+a2.x+a3.x, a0.y+a1.y+a2.y+a3.y,
                             a0.z+a1.z+a2.z+a3.z, a0.w+a1.w+a2.w+a3.w);

    __shared__ float4 red[256];
    red[tid] = acc;
    __syncthreads();
    if (tid < 64) {
        float4 a = red[tid], bb = red[tid + 64], c = red[tid + 128], d = red[tid + 192];
        float4 s = make_float4(a.x + bb.x + c.x + d.x, a.y + bb.y + c.y + d.y,
                               a.z + bb.z + c.z + d.z, a.w + bb.w + c.w + d.w);
        ((float4*)u_part)[((size_t)b * GCH + grp) * (D / 4) + tid] = s;
    }
}

// ---------------------------------------------------------------------------
// Head: u = sum_g u_part ; y = u@W1 + sw*b1 ; p = y@W2/L + b2 ;
//       out = relu(p@fc1_w + fc1_b).
// 1024 threads: t = output col, s = 4-way k-split. sw summed from 8 partials.
// ---------------------------------------------------------------------------
__global__ __launch_bounds__(1024) void head_kernel(
    const float* __restrict__ u_part, const float* __restrict__ sw_part,
    const float* __restrict__ W1, const float* __restrict__ b1,
    const float* __restrict__ W2, const float* __restrict__ b2,
    const float* __restrict__ fc1_w, const float* __restrict__ fc1_b,
    const int* __restrict__ cur_len, float* __restrict__ out)
{
    const int b = blockIdx.x;
    const int t = threadIdx.x & 255;   // output column
    const int s = threadIdx.x >> 8;    // k-split group (0..3)
    __shared__ float red[4][256];
    __shared__ float su[D];
    __shared__ float sy[H];
    __shared__ float sp[H];

    float part = 0.f;
    #pragma unroll
    for (int c = 0; c < GCH / 4; ++c)
        part += u_part[((size_t)b * GCH + s * (GCH / 4) + c) * D + t];
    red[s][t] = part;
    __syncthreads();
    if (s == 0) su[t] = red[0][t] + red[1][t] + red[2][t] + red[3][t];
    __syncthreads();

    part = 0.f;
    #pragma unroll 8
    for (int k = 0; k < 64; ++k) {
        const int d = s * 64 + k;
        part += su[d] * W1[d * H + t];
    }
    red[s][t] = part;
    __syncthreads();
    if (s == 0) {
        float sw = 0.f;
        #pragma unroll
        for (int i = 0; i < SEG; ++i) sw += sw_part[b * SEG + i];
        sy[t] = red[0][t] + red[1][t] + red[2][t] + red[3][t] + sw * b1[t];
    }
    __syncthreads();

    const float invL = 1.f / (float)(*cur_len);
    part = 0.f;
    #pragma unroll 8
    for (int k = 0; k < 64; ++k) {
        const int d = s * 64 + k;
        part += sy[d] * W2[d * H + t];
    }
    red[s][t] = part;
    __syncthreads();
    if (s == 0)
        sp[t] = (red[0][t] + red[1][t] + red[2][t] + red[3][t]) * invL + b2[t];
    __syncthreads();

    part = 0.f;
    #pragma unroll 8
    for (int k = 0; k < 64; ++k) {
        const int d = s * 64 + k;
        part += sp[d] * fc1_w[d * H + t];
    }
    red[s][t] = part;
    __syncthreads();
    if (s == 0) {
        const float v = red[0][t] + red[1][t] + red[2][t] + red[3][t] + fc1_b[t];
        out[(size_t)b * H + t] = fmaxf(v, 0.f);
    }
}

extern "C" void kernel_launch(void* const* d_in, const int* in_sizes, int n_in,
                              void* d_out, int out_size, void* d_ws, size_t ws_size,
                              hipStream_t stream) {
    const int*   neighbors = (const int*)  d_in[0];
    const int*   adj_row   = (const int*)  d_in[1];
    const int*   adj_col   = (const int*)  d_in[2];
    const float* adj_val   = (const float*)d_in[3];
    const float* emb_table = (const float*)d_in[4];
    const float* W1        = (const float*)d_in[5];
    const float* b1        = (const float*)d_in[6];
    const float* W2        = (const float*)d_in[7];
    const float* b2        = (const float*)d_in[8];
    const float* fc1_w     = (const float*)d_in[9];
    const float* fc1_b     = (const float*)d_in[10];
    const int*   cur_len   = (const int*)  d_in[11];
    float*       out       = (float*)d_out;

    // workspace layout (floats):
    // [w: B*N][z: B*N]  <- zeroed by zero_wz_kernel (atomic accumulation)
    // [sw_part: B*SEG][u_part: B*GCH*D]  <- fully overwritten
    float* w_ws  = (float*)d_ws;
    float* z_ws  = w_ws + (size_t)B * N;
    float* sw_ws = z_ws + (size_t)B * N;          // 16B-aligned
    float* u_ws  = sw_ws + (size_t)B * SEG;       // 16B-aligned (B*SEG=512)

    // zero w|z: 2*B*N floats = 65536 float4 -> 128 blocks x 512 threads
    zero_wz_kernel<<<128, 512, 0, stream>>>(w_ws);
    edge_w_kernel<<<dim3(B, SEG), 512, 0, stream>>>(adj_row, adj_col, adj_val,
                                                    cur_len, w_ws, sw_ws);
    edge_z_kernel<<<dim3(B, SEG), 512, 0, stream>>>(adj_row, adj_col, adj_val,
                                                    w_ws, z_ws);
    gather_kernel<<<dim3(B, GCH), 256, 0, stream>>>(neighbors, emb_table, z_ws, u_ws);
    head_kernel<<<B, 1024, 0, stream>>>(u_ws, sw_ws, W1, b1, W2, b2,
                                        fc1_w, fc1_b, cur_len, out);
}

// Round 4
// 222.748 us; speedup vs baseline: 1.1540x; 1.0959x over previous
//
#include <hip/hip_runtime.h>

#define B 64
#define N 2048
#define E 32768
#define D 256
#define H 256
#define GCH 32         // gather blocks per batch (64 rows per block; 2048 blocks)
#define SEG 8          // edge segments per batch
#define EPB (E / SEG)  // 4096 edges per block

// ---------------------------------------------------------------------------
// Edge pass 1 (Round-0 measured-best): w_part[b,seg,n], sw_part[b,seg].
// ---------------------------------------------------------------------------
__global__ __launch_bounds__(512) void edge_w_kernel(
    const int* __restrict__ adj_row, const int* __restrict__ adj_col,
    const float* __restrict__ adj_val, const int* __restrict__ cur_len,
    float* __restrict__ w_part, float* __restrict__ sw_part)
{
    __shared__ float wloc[N];
    __shared__ float sred[8];
    const int b = blockIdx.x, seg = blockIdx.y, tid = threadIdx.x;
    const int L = *cur_len;

    ((float4*)wloc)[tid] = make_float4(0.f, 0.f, 0.f, 0.f);
    __syncthreads();

    const int base = b * E + seg * EPB;            // multiple of 4096 -> aligned
    const int4*   row4 = (const int4*)  (adj_row + base);
    const int4*   col4 = (const int4*)  (adj_col + base);
    const float4* val4 = (const float4*)(adj_val + base);

    float svp = 0.f;
    #pragma unroll
    for (int k = 0; k < EPB / (512 * 4); ++k) {    // 2 iterations
        const int    i = tid + k * 512;
        const int4   r = row4[i];
        const int4   c = col4[i];
        const float4 v = val4[i];
        if (r.x < L) { atomicAdd(&wloc[c.x], v.x); svp += v.x; }
        if (r.y < L) { atomicAdd(&wloc[c.y], v.y); svp += v.y; }
        if (r.z < L) { atomicAdd(&wloc[c.z], v.z); svp += v.z; }
        if (r.w < L) { atomicAdd(&wloc[c.w], v.w); svp += v.w; }
    }
    __syncthreads();

    float4* dst = (float4*)(w_part + ((size_t)b * SEG + seg) * N);
    dst[tid] = ((const float4*)wloc)[tid];

    for (int off = 32; off; off >>= 1) svp += __shfl_down(svp, off, 64);
    if ((tid & 63) == 0) sred[tid >> 6] = svp;
    __syncthreads();
    if (tid == 0) {
        float s = 0.f;
        #pragma unroll
        for (int i = 0; i < 8; ++i) s += sred[i];
        sw_part[b * SEG + seg] = s;
    }
}

// ---------------------------------------------------------------------------
// Edge pass 2 (Round-0 measured-best): rebuild w[b,:] from 8 partials, then
// z_part[b,seg,m] = sum_{e in seg: col==m} w[row[e]] * val[e].
// ---------------------------------------------------------------------------
__global__ __launch_bounds__(512) void edge_z_kernel(
    const int* __restrict__ adj_row, const int* __restrict__ adj_col,
    const float* __restrict__ adj_val, const float* __restrict__ w_part,
    float* __restrict__ z_part)
{
    __shared__ float wfull[N];
    __shared__ float zloc[N];
    const int b = blockIdx.x, seg = blockIdx.y, tid = threadIdx.x;

    const float4* wp4 = (const float4*)(w_part + (size_t)b * SEG * N);
    float4 s = make_float4(0.f, 0.f, 0.f, 0.f);
    #pragma unroll
    for (int sg = 0; sg < SEG; ++sg) {
        const float4 v = wp4[sg * (N / 4) + tid];
        s.x += v.x; s.y += v.y; s.z += v.z; s.w += v.w;
    }
    ((float4*)wfull)[tid] = s;
    ((float4*)zloc)[tid]  = make_float4(0.f, 0.f, 0.f, 0.f);
    __syncthreads();

    const int base = b * E + seg * EPB;
    const int4*   row4 = (const int4*)  (adj_row + base);
    const int4*   col4 = (const int4*)  (adj_col + base);
    const float4* val4 = (const float4*)(adj_val + base);

    #pragma unroll
    for (int k = 0; k < EPB / (512 * 4); ++k) {    // 2 iterations
        const int    i = tid + k * 512;
        const int4   r = row4[i];
        const int4   c = col4[i];
        const float4 v = val4[i];
        float wv;
        wv = wfull[r.x]; if (wv != 0.f) atomicAdd(&zloc[c.x], wv * v.x);
        wv = wfull[r.y]; if (wv != 0.f) atomicAdd(&zloc[c.y], wv * v.y);
        wv = wfull[r.z]; if (wv != 0.f) atomicAdd(&zloc[c.z], wv * v.z);
        wv = wfull[r.w]; if (wv != 0.f) atomicAdd(&zloc[c.w], wv * v.w);
    }
    __syncthreads();

    float4* dst = (float4*)(z_part + ((size_t)b * SEG + seg) * N);
    dst[tid] = ((const float4*)zloc)[tid];
}

// ---------------------------------------------------------------------------
// Gather v2: u_part[b,g,:] = sum_{n in group g} z[b,n]*emb[neighbors[b,n],:]
// CHANGE vs Round 0: all 16 row-loads per wave are explicitly staged into a
// statically-indexed float4[16] register array BEFORE any accumulation ->
// forced 16-deep MLP (the load/use interleave let the compiler keep only a
// few loads in flight; gather ran at 2.4 TB/s effective = latency-bound).
// ~64 VGPR of load data + acc -> ~4-5 waves/SIMD, still 16+ waves/CU.
// ---------------------------------------------------------------------------
__global__ __launch_bounds__(256) void gather_kernel(
    const int* __restrict__ neighbors, const float* __restrict__ emb,
    const float* __restrict__ z_part, float* __restrict__ u_part)
{
    const int b = blockIdx.x, grp = blockIdx.y, tid = threadIdx.x;
    const int lane = tid & 63, rg = tid >> 6;
    const int n0 = grp * 64;                  // 64 rows per block

    __shared__ float zh[2][64];
    __shared__ int   ns[64];
    if (tid < 128) {
        const int j = tid & 63, half = tid >> 6;
        float s = 0.f;
        #pragma unroll
        for (int sg = 0; sg < SEG / 2; ++sg)
            s += z_part[((size_t)b * SEG + half * (SEG / 2) + sg) * N + n0 + j];
        zh[half][j] = s;
        if (half == 0) ns[j] = neighbors[(size_t)b * N + n0 + j];
    }
    __syncthreads();

    const float4* __restrict__ emb4 = (const float4*)emb;

    // phase 1: issue all 16 independent row loads (static indices -> regs)
    float4 v[16];
    #pragma unroll
    for (int i = 0; i < 16; ++i) {
        const int j = i * 4 + rg;
        v[i] = emb4[(size_t)ns[j] * (D / 4) + lane];
    }

    // phase 2: accumulate
    float4 acc = make_float4(0.f, 0.f, 0.f, 0.f);
    #pragma unroll
    for (int i = 0; i < 16; ++i) {
        const int j = i * 4 + rg;
        const float zv = zh[0][j] + zh[1][j];
        acc.x += zv * v[i].x; acc.y += zv * v[i].y;
        acc.z += zv * v[i].z; acc.w += zv * v[i].w;
    }

    __shared__ float4 red[256];
    red[tid] = acc;
    __syncthreads();
    if (tid < 64) {
        float4 a = red[tid], bb = red[tid + 64], c = red[tid + 128], d = red[tid + 192];
        float4 s = make_float4(a.x + bb.x + c.x + d.x, a.y + bb.y + c.y + d.y,
                               a.z + bb.z + c.z + d.z, a.w + bb.w + c.w + d.w);
        ((float4*)u_part)[((size_t)b * GCH + grp) * (D / 4) + tid] = s;
    }
}

// ---------------------------------------------------------------------------
// Head (Round-0 measured-best): u = sum_g u_part ; y = u@W1 + sw*b1 ;
// p = y@W2/L + b2 ; out = relu(p@fc1_w + fc1_b).
// ---------------------------------------------------------------------------
__global__ __launch_bounds__(1024) void head_kernel(
    const float* __restrict__ u_part, const float* __restrict__ sw_part,
    const float* __restrict__ W1, const float* __restrict__ b1,
    const float* __restrict__ W2, const float* __restrict__ b2,
    const float* __restrict__ fc1_w, const float* __restrict__ fc1_b,
    const int* __restrict__ cur_len, float* __restrict__ out)
{
    const int b = blockIdx.x;
    const int t = threadIdx.x & 255;   // output column
    const int s = threadIdx.x >> 8;    // k-split group (0..3)
    __shared__ float red[4][256];
    __shared__ float su[D];
    __shared__ float sy[H];
    __shared__ float sp[H];

    float part = 0.f;
    #pragma unroll
    for (int c = 0; c < GCH / 4; ++c)
        part += u_part[((size_t)b * GCH + s * (GCH / 4) + c) * D + t];
    red[s][t] = part;
    __syncthreads();
    if (s == 0) su[t] = red[0][t] + red[1][t] + red[2][t] + red[3][t];
    __syncthreads();

    part = 0.f;
    #pragma unroll 8
    for (int k = 0; k < 64; ++k) {
        const int d = s * 64 + k;
        part += su[d] * W1[d * H + t];
    }
    red[s][t] = part;
    __syncthreads();
    if (s == 0) {
        float sw = 0.f;
        #pragma unroll
        for (int i = 0; i < SEG; ++i) sw += sw_part[b * SEG + i];
        sy[t] = red[0][t] + red[1][t] + red[2][t] + red[3][t] + sw * b1[t];
    }
    __syncthreads();

    const float invL = 1.f / (float)(*cur_len);
    part = 0.f;
    #pragma unroll 8
    for (int k = 0; k < 64; ++k) {
        const int d = s * 64 + k;
        part += sy[d] * W2[d * H + t];
    }
    red[s][t] = part;
    __syncthreads();
    if (s == 0)
        sp[t] = (red[0][t] + red[1][t] + red[2][t] + red[3][t]) * invL + b2[t];
    __syncthreads();

    part = 0.f;
    #pragma unroll 8
    for (int k = 0; k < 64; ++k) {
        const int d = s * 64 + k;
        part += sp[d] * fc1_w[d * H + t];
    }
    red[s][t] = part;
    __syncthreads();
    if (s == 0) {
        const float v = red[0][t] + red[1][t] + red[2][t] + red[3][t] + fc1_b[t];
        out[(size_t)b * H + t] = fmaxf(v, 0.f);
    }
}

extern "C" void kernel_launch(void* const* d_in, const int* in_sizes, int n_in,
                              void* d_out, int out_size, void* d_ws, size_t ws_size,
                              hipStream_t stream) {
    const int*   neighbors = (const int*)  d_in[0];
    const int*   adj_row   = (const int*)  d_in[1];
    const int*   adj_col   = (const int*)  d_in[2];
    const float* adj_val   = (const float*)d_in[3];
    const float* emb_table = (const float*)d_in[4];
    const float* W1        = (const float*)d_in[5];
    const float* b1        = (const float*)d_in[6];
    const float* W2        = (const float*)d_in[7];
    const float* b2        = (const float*)d_in[8];
    const float* fc1_w     = (const float*)d_in[9];
    const float* fc1_b     = (const float*)d_in[10];
    const int*   cur_len   = (const int*)  d_in[11];
    float*       out       = (float*)d_out;

    // workspace layout (floats), all fully overwritten every call (no memset):
    // [w_part: B*SEG*N][z_part: B*SEG*N][sw_part: B*SEG][u_part: B*GCH*D]
    float* wp_ws = (float*)d_ws;
    float* zp_ws = wp_ws + (size_t)B * SEG * N;
    float* sw_ws = zp_ws + (size_t)B * SEG * N;
    float* u_ws  = sw_ws + (size_t)B * SEG;     // 16B-aligned (B*SEG=512)

    edge_w_kernel<<<dim3(B, SEG), 512, 0, stream>>>(adj_row, adj_col, adj_val,
                                                    cur_len, wp_ws, sw_ws);
    edge_z_kernel<<<dim3(B, SEG), 512, 0, stream>>>(adj_row, adj_col, adj_val,
                                                    wp_ws, zp_ws);
    gather_kernel<<<dim3(B, GCH), 256, 0, stream>>>(neighbors, emb_table, zp_ws, u_ws);
    head_kernel<<<B, 1024, 0, stream>>>(u_ws, sw_ws, W1, b1, W2, b2,
                                        fc1_w, fc1_b, cur_len, out);
}